// Round 2
// baseline (713.123 us; speedup 1.0000x reference)
//
#include <hip/hip_runtime.h>
#include <cstdint>
#include <cstddef>

// Problem constants
#define TT   2048
#define BB   64
#define KK   512
#define OO   512
#define OT   64      // o-range per block (4 waves x 2x2 split)
#define NCH  32      // time chunks
#define TC   64      // t-steps per chunk
#define NIT  256     // iterations per block: (TC/2) j x 8 kc

typedef __attribute__((ext_vector_type(8))) short short8;
typedef __attribute__((ext_vector_type(4))) float f32x4;

__device__ __forceinline__ unsigned int f2bf(float f) {
  unsigned int u = __float_as_uint(f);
  unsigned int rounding = 0x7FFFu + ((u >> 16) & 1u);
  return (u + rounding) >> 16;
}

__device__ __forceinline__ float sigmoid_f(float z) {
  return 1.0f / (1.0f + __expf(-z));
}

__device__ __forceinline__ float tanh_f(float z) {
  z = fminf(15.0f, fmaxf(-15.0f, z));
  float e = __expf(-2.0f * z);
  return (1.0f - e) / (1.0f + e);
}

__device__ __forceinline__ void async_ld16(const void* g, void* l) {
  __builtin_amdgcn_global_load_lds(
      (const __attribute__((address_space(1))) void*)g,
      (__attribute__((address_space(3))) void*)l, 16, 0, 0);
}

// ---------------- kernel 1: x fp32 -> bf16 (32B read / 16B write per iter) --
__global__ void convert_x_k(const float4* __restrict__ x4,
                            uint4* __restrict__ xb8, int n8) {
  int i = blockIdx.x * blockDim.x + threadIdx.x;
  int stride = gridDim.x * blockDim.x;
  for (; i < n8; i += stride) {
    float4 a = x4[2 * i];
    float4 b = x4[2 * i + 1];
    uint4 o;
    o.x = f2bf(a.x) | (f2bf(a.y) << 16);
    o.y = f2bf(a.z) | (f2bf(a.w) << 16);
    o.z = f2bf(b.x) | (f2bf(b.y) << 16);
    o.w = f2bf(b.z) | (f2bf(b.w) << 16);
    xb8[i] = o;
  }
}

// ---------------- kernel 2: transpose+convert weights ----------------
// Gt[o][k] = bf16(g[k][o]); Ht likewise. grid (16,16,2), block (32,8)
__global__ void prep_weights_k(const float* __restrict__ g,
                               const float* __restrict__ h,
                               unsigned short* __restrict__ Gt,
                               unsigned short* __restrict__ Ht) {
  __shared__ float tile[32][33];
  const float* src = (blockIdx.z == 0) ? g : h;
  unsigned short* dst = (blockIdx.z == 0) ? Gt : Ht;
  int ox = blockIdx.x * 32;   // o base
  int ky = blockIdx.y * 32;   // k base
  int tx = threadIdx.x, ty = threadIdx.y;
  #pragma unroll
  for (int r = ty; r < 32; r += 8)
    tile[r][tx] = src[(ky + r) * OO + ox + tx];
  __syncthreads();
  #pragma unroll
  for (int r = ty; r < 32; r += 8)
    dst[(size_t)(ox + r) * KK + ky + tx] = (unsigned short)f2bf(tile[tx][r]);
}

// ---------------- kernel 3: persistent-weight fused GEMM + gates + scan -----
// 256 blocks (1/CU), 256 threads. LDS: Wlds[128][512] bf16 (128KB, persistent)
// + A double buffer 2x[128][64] bf16 (32KB). Single barrier per kc.
__global__ __launch_bounds__(256, 1) void rnn_fused2_k(
    const unsigned short* __restrict__ xb,   // [T*B][K] bf16
    const unsigned short* __restrict__ Gt,   // [OO][KK] bf16
    const unsigned short* __restrict__ Ht,   // [OO][KK] bf16
    const float* __restrict__ gb, const float* __restrict__ hb,
    const float* __restrict__ r,  const float* __restrict__ rb,
    float* __restrict__ chunkA, float* __restrict__ chunkB) {
  extern __shared__ __align__(16) unsigned short smem[];
  unsigned short* Wlds = smem;            // [128][512]  rows 0-63 G, 64-127 H
  unsigned short* Ab   = smem + 65536;    // [2][128][64]

  const int tid  = threadIdx.x;
  const int wave = tid >> 6;
  const int lane = tid & 63;
  const int quad = lane >> 4;
  const int lcol = lane & 15;
  const int srow8 = lane >> 3;
  const int sch   = lane & 7;

  // XCD-swizzle: the 8 o-tiles of one chunk land on one XCD (idx%8 heuristic)
  const int bi = blockIdx.x;
  const int q  = bi >> 3;
  const int c  = (bi & 7) * 4 + (q >> 3);   // 0..31
  const int ot = q & 7;                     // 0..7
  const int o0 = ot * OT;

  const int ow = wave & 1;   // o-half (32 o's)
  const int bh = wave >> 1;  // b-half (32 b's, both timesteps)
  const int ob = o0 + ow * 32;

  float gbv[2], hbv[2], rv[2], rbv[2];
  #pragma unroll
  for (int n = 0; n < 2; n++) {
    int o = ob + n * 16 + lcol;
    gbv[n] = gb[o]; hbv[n] = hb[o]; rv[n] = r[o]; rbv[n] = rb[o];
  }

  // ---- stage weights once (32 x 1KB rows per wave, async, XOR-swizzled) ----
  for (int rr = 0; rr < 32; ++rr) {
    int row = wave * 32 + rr;  // 0..127
    const unsigned short* Wsrc = (row < 64)
        ? (Gt + (size_t)(o0 + row) * KK)
        : (Ht + (size_t)(o0 + row - 64) * KK);
    int gch = (lane & 56) | ((lane & 7) ^ (row & 7));
    async_ld16(Wsrc + gch * 8, Wlds + row * 512);
  }

  auto stage_a = [&](int n, int pbuf) {
    int jj = n >> 3, kcc = n & 7;
    size_t R0 = (size_t)(c * TC + jj * 2) * BB;
    unsigned short* dst = Ab + pbuf * 8192;
    #pragma unroll
    for (int ii = 0; ii < 4; ++ii) {
      int row = wave * 32 + ii * 8 + srow8;
      int gch = sch ^ (row & 7);
      const unsigned short* gp = xb + (R0 + row) * KK + kcc * 64 + gch * 8;
      async_ld16(gp, dst + (wave * 32 + ii * 8) * 64);
    }
  };

  stage_a(0, 0);
  __syncthreads();   // drains weights + A0 (vmcnt(0) implied)

  // chunk-scan state per (b,o) slot: y_out = SB + SA*y_in
  float SA[16], SB[16];
  #pragma unroll
  for (int s = 0; s < 16; s++) { SA[s] = 1.0f; SB[s] = 0.0f; }

  f32x4 acc[4][4];  // [am: tsel*2+mt][bn: n*2+gh]
  #pragma unroll
  for (int a = 0; a < 4; a++)
    #pragma unroll
    for (int b = 0; b < 4; b++) {
      f32x4 z = {0.0f, 0.0f, 0.0f, 0.0f};
      acc[a][b] = z;
    }

  int p = 0;
  for (int it = 0; it < NIT; ++it) {
    if (it + 1 < NIT) stage_a(it + 1, p ^ 1);   // prefetch overlaps compute

    const unsigned short* A0 = Ab + p * 8192;
    const int kc = it & 7;
    #pragma unroll
    for (int ks = 0; ks < 2; ++ks) {
      short8 bfr[4];
      #pragma unroll
      for (int n = 0; n < 2; ++n)
        #pragma unroll
        for (int gh = 0; gh < 2; ++gh) {
          int rowb = gh * 64 + ow * 32 + n * 16 + lcol;
          int cb = kc * 8 + ks * 4 + quad;
          int slot = (cb & ~7) | ((cb & 7) ^ (rowb & 7));
          bfr[n * 2 + gh] = *(const short8*)(Wlds + rowb * 512 + slot * 8);
        }
      #pragma unroll
      for (int am = 0; am < 4; ++am) {
        int arow = (am >> 1) * 64 + bh * 32 + (am & 1) * 16 + lcol;
        int lc = ks * 4 + quad;
        int slot = lc ^ (arow & 7);
        short8 afr = *(const short8*)(A0 + arow * 64 + slot * 8);
        #pragma unroll
        for (int bn = 0; bn < 4; ++bn)
          acc[am][bn] = __builtin_amdgcn_mfma_f32_16x16x32_bf16(
              afr, bfr[bn], acc[am][bn], 0, 0, 0);
      }
    }

    if ((it & 7) == 7) {
      // epilogue for j = it>>3: activations + time gate + 2-step composition
      const int j = it >> 3;
      const int t0 = c * TC + j * 2;
      #pragma unroll
      for (int n = 0; n < 2; ++n) {
        float rt0 = 2.0f * sigmoid_f(((float)t0       * (1.0f / TT)) * rv[n] + rbv[n]);
        float rt1 = 2.0f * sigmoid_f(((float)(t0 + 1) * (1.0f / TT)) * rv[n] + rbv[n]);
        #pragma unroll
        for (int mt = 0; mt < 2; ++mt)
          #pragma unroll
          for (int reg = 0; reg < 4; ++reg) {
            float G0 = sigmoid_f(acc[mt    ][n * 2 + 0][reg] + gbv[n]) * rt0;
            float H0 = tanh_f  (acc[mt    ][n * 2 + 1][reg] + hbv[n]) * rt0;
            float G1 = sigmoid_f(acc[2 + mt][n * 2 + 0][reg] + gbv[n]) * rt1;
            float H1 = tanh_f  (acc[2 + mt][n * 2 + 1][reg] + hbv[n]) * rt1;
            float pA = G1 * G0;
            float pB = fmaf(G1, H0, H1);
            int s = (n * 2 + mt) * 4 + reg;
            SB[s] = fmaf(pA, SB[s], pB);
            SA[s] *= pA;
            acc[mt][n * 2 + 0][reg] = 0.0f;
            acc[mt][n * 2 + 1][reg] = 0.0f;
            acc[2 + mt][n * 2 + 0][reg] = 0.0f;
            acc[2 + mt][n * 2 + 1][reg] = 0.0f;
          }
      }
    }
    __syncthreads();   // drains this iter's prefetch; releases buf p
    p ^= 1;
  }

  // write chunk composition: layout [c][b][o]
  #pragma unroll
  for (int n = 0; n < 2; ++n)
    #pragma unroll
    for (int mt = 0; mt < 2; ++mt)
      #pragma unroll
      for (int reg = 0; reg < 4; ++reg) {
        int s = (n * 2 + mt) * 4 + reg;
        int b = bh * 32 + mt * 16 + quad * 4 + reg;
        int o = ob + n * 16 + lcol;
        size_t idx = ((size_t)c * BB + b) * OO + o;
        chunkA[idx] = SA[s];
        chunkB[idx] = SB[s];
      }
}

// ---------------- kernel 4: fold chunks ----------------
__global__ void combine_k(const float* __restrict__ cA,
                          const float* __restrict__ cB,
                          float* __restrict__ out) {
  int i = blockIdx.x * blockDim.x + threadIdx.x;  // b*OO + o
  float y = 0.0f;
  #pragma unroll
  for (int c = 0; c < NCH; c++) {
    float A  = cA[(size_t)c * (BB * OO) + i];
    float Bv = cB[(size_t)c * (BB * OO) + i];
    y = fmaf(A, y, Bv);
  }
  out[i] = y;
}

extern "C" void kernel_launch(void* const* d_in, const int* in_sizes, int n_in,
                              void* d_out, int out_size, void* d_ws, size_t ws_size,
                              hipStream_t stream) {
  (void)in_sizes; (void)n_in; (void)out_size; (void)ws_size;
  const float* x  = (const float*)d_in[0];
  const float* g  = (const float*)d_in[1];
  const float* gb = (const float*)d_in[2];
  const float* h  = (const float*)d_in[3];
  const float* hb = (const float*)d_in[4];
  const float* r  = (const float*)d_in[5];
  const float* rb = (const float*)d_in[6];
  float* out = (float*)d_out;

  char* w = (char*)d_ws;
  unsigned short* xb = (unsigned short*)w;                       // 134217728 B
  unsigned short* Gt = (unsigned short*)(w + 134217728);         // 524288 B
  unsigned short* Ht = (unsigned short*)(w + 134742016);         // 524288 B
  float* chunkA = (float*)(w + 135266304);                       // 4194304 B
  float* chunkB = (float*)(w + 139460608);                       // 4194304 B
  // total: 143654912 B

  static bool attr_set = false;
  if (!attr_set) {
    hipFuncSetAttribute(reinterpret_cast<const void*>(rnn_fused2_k),
                        hipFuncAttributeMaxDynamicSharedMemorySize, 163840);
    attr_set = true;
  }

  const int n8 = (TT * BB * KK) / 8;  // 8388608
  convert_x_k<<<4096, 256, 0, stream>>>((const float4*)x, (uint4*)xb, n8);
  prep_weights_k<<<dim3(16, 16, 2), dim3(32, 8), 0, stream>>>(g, h, Gt, Ht);
  rnn_fused2_k<<<NCH * (OO / OT), 256, 163840, stream>>>(xb, Gt, Ht, gb, hb,
                                                         r, rb, chunkA, chunkB);
  combine_k<<<(BB * OO) / 128, 128, 0, stream>>>(chunkA, chunkB, out);
}

// Round 3
// 539.460 us; speedup vs baseline: 1.3219x; 1.3219x over previous
//
#include <hip/hip_runtime.h>
#include <cstdint>
#include <cstddef>

// Problem constants
#define TT   2048
#define BB   64
#define KK   512
#define OO   512
#define NCH  64      // time chunks
#define TC   32      // t-steps per chunk (1 t-step per iteration)

typedef __attribute__((ext_vector_type(8))) short short8;
typedef __attribute__((ext_vector_type(4))) float f32x4;

__device__ __forceinline__ unsigned short f2bf(float f) {
  unsigned int u = __float_as_uint(f);
  unsigned int rounding = 0x7FFFu + ((u >> 16) & 1u);
  return (unsigned short)((u + rounding) >> 16);
}

__device__ __forceinline__ float sigmoid_f(float z) {
  return 1.0f / (1.0f + __expf(-z));
}

__device__ __forceinline__ float tanh_f(float z) {
  z = fminf(15.0f, fmaxf(-15.0f, z));
  float e = __expf(-2.0f * z);
  return (1.0f - e) / (1.0f + e);
}

__device__ __forceinline__ void async_ld16(const void* g, void* l) {
  __builtin_amdgcn_global_load_lds(
      (const __attribute__((address_space(1))) void*)g,
      (__attribute__((address_space(3))) void*)l, 16, 0, 0);
}

// ---------------- kernel 1: x fp32 -> bf16 ----------------
__global__ void convert_x_k(const float4* __restrict__ x4,
                            ushort4* __restrict__ xb4, int n4) {
  int i = blockIdx.x * blockDim.x + threadIdx.x;
  int stride = gridDim.x * blockDim.x;
  for (; i < n4; i += stride) {
    float4 v = x4[i];
    ushort4 o;
    o.x = f2bf(v.x); o.y = f2bf(v.y); o.z = f2bf(v.z); o.w = f2bf(v.w);
    xb4[i] = o;
  }
}

// ---------------- kernel 2: transpose+convert weights ----------------
// Gt[o][k] = bf16(g[k][o]); Ht likewise. grid (16,16,2), block (32,8)
__global__ void prep_weights_k(const float* __restrict__ g,
                               const float* __restrict__ h,
                               unsigned short* __restrict__ Gt,
                               unsigned short* __restrict__ Ht) {
  __shared__ float tile[32][33];
  const float* src = (blockIdx.z == 0) ? g : h;
  unsigned short* dst = (blockIdx.z == 0) ? Gt : Ht;
  int ox = blockIdx.x * 32;   // o base
  int ky = blockIdx.y * 32;   // k base
  int tx = threadIdx.x, ty = threadIdx.y;
  #pragma unroll
  for (int r = ty; r < 32; r += 8)
    tile[r][tx] = src[(ky + r) * OO + ox + tx];
  __syncthreads();
  #pragma unroll
  for (int r = ty; r < 32; r += 8)
    dst[(size_t)(ox + r) * KK + ky + tx] = f2bf(tile[tx][r]);
}

// ---------------- kernel 3: register-B fused GEMM + gates + scan ----------
// 256 blocks (1/CU), 512 threads (8 waves = 2/SIMD). Weights live in VGPRs:
// wave w owns o-cols [ot*128 + 16w, +16) of BOTH G and H (128 VGPRs).
// Per it = 1 t-step: A-tile 64 rows x 512 k staged to LDS (64 KB, dbuf).
// Zero B traffic after init; 256 FLOP per staged A-byte.
__global__ __launch_bounds__(512, 2) void rnn_fused3_k(
    const unsigned short* __restrict__ xb,   // [T*B][K] bf16
    const unsigned short* __restrict__ Gt,   // [OO][KK] bf16
    const unsigned short* __restrict__ Ht,   // [OO][KK] bf16
    const float* __restrict__ gb, const float* __restrict__ hb,
    const float* __restrict__ r,  const float* __restrict__ rb,
    float* __restrict__ chunkA, float* __restrict__ chunkB) {
  extern __shared__ __align__(16) unsigned short smem[];  // 2 x [64][512]

  const int tid  = threadIdx.x;
  const int wave = tid >> 6;   // 0..7
  const int lane = tid & 63;
  const int quad = lane >> 4;
  const int lcol = lane & 15;

  // bi = ot*64 + c: the 4 o-tiles of chunk c share bi%8 -> same XCD (L2 reuse)
  const int bi = blockIdx.x;
  const int ot = bi >> 6;      // 0..3
  const int c  = bi & 63;      // 0..63
  const int o  = ot * 128 + wave * 16 + lcol;   // this thread's output column

  const float gbv = gb[o], hbv = hb[o];
  const float rv  = r[o],  rbv = rb[o];

  // ---- weights into registers: 16 cols x K512 x {G,H} = 128 VGPRs ----
  short8 Bg[8][2], Bh[8][2];
  {
    const unsigned short* gp = Gt + (size_t)o * KK + quad * 8;
    const unsigned short* hp = Ht + (size_t)o * KK + quad * 8;
    #pragma unroll
    for (int kc = 0; kc < 8; ++kc)
      #pragma unroll
      for (int ks = 0; ks < 2; ++ks) {
        Bg[kc][ks] = *(const short8*)(gp + kc * 64 + ks * 32);
        Bh[kc][ks] = *(const short8*)(hp + kc * 64 + ks * 32);
      }
  }

  // stage A-tile for absolute t-step trow into buffer buf (64 rows x 512 k).
  // One DMA instr per row: lane L writes LDS 16B-slot L of the row; the
  // global 16B chunk is XOR-swizzled so reads are 2-way-max on banks.
  auto stage = [&](int trow, int buf) {
    unsigned short* dst = smem + buf * 32768 + wave * 8 * 512;
    const unsigned short* src = xb + ((size_t)trow * BB + wave * 8) * KK;
    #pragma unroll
    for (int rr = 0; rr < 8; ++rr) {
      int gch = (lane & ~7) | ((lane & 7) ^ rr);   // (row&7)==rr here
      async_ld16(src + rr * KK + gch * 8, dst + rr * 512);
    }
  };

  stage(c * TC, 0);

  // chunk-scan state per (b,o) slot: y_out = SB + SA*y_in
  float SA[16], SB[16];
  #pragma unroll
  for (int s = 0; s < 16; s++) { SA[s] = 1.0f; SB[s] = 0.0f; }

  f32x4 accG[4], accH[4];
  #pragma unroll
  for (int m = 0; m < 4; m++) {
    f32x4 z = {0.0f, 0.0f, 0.0f, 0.0f};
    accG[m] = z; accH[m] = z;
  }

  __syncthreads();   // drains weight loads + A0 (vmcnt(0) implied)

  int p = 0;
  for (int it = 0; it < TC; ++it) {
    if (it + 1 < TC) stage(c * TC + it + 1, p ^ 1);   // prefetch next t

    const unsigned short* A0 = smem + p * 32768;
    #pragma unroll
    for (int kc = 0; kc < 8; ++kc)
      #pragma unroll
      for (int ks = 0; ks < 2; ++ks)
        #pragma unroll
        for (int mt = 0; mt < 4; ++mt) {
          int arow = mt * 16 + lcol;
          int slot = kc * 8 + ((ks * 4 + quad) ^ (arow & 7));
          short8 a = *(const short8*)(A0 + arow * 512 + slot * 8);
          accG[mt] = __builtin_amdgcn_mfma_f32_16x16x32_bf16(
              a, Bg[kc][ks], accG[mt], 0, 0, 0);
          accH[mt] = __builtin_amdgcn_mfma_f32_16x16x32_bf16(
              a, Bh[kc][ks], accH[mt], 0, 0, 0);
        }

    // epilogue: one t-step of the recurrence, folded into (SA,SB)
    const int t = c * TC + it;
    const float rt = 2.0f * sigmoid_f(((float)t * (1.0f / TT)) * rv + rbv);
    #pragma unroll
    for (int mt = 0; mt < 4; ++mt)
      #pragma unroll
      for (int reg = 0; reg < 4; ++reg) {
        float G = sigmoid_f(accG[mt][reg] + gbv) * rt;
        float H = tanh_f  (accH[mt][reg] + hbv) * rt;
        int s = mt * 4 + reg;
        SB[s] = fmaf(G, SB[s], H);
        SA[s] *= G;
        accG[mt][reg] = 0.0f;
        accH[mt][reg] = 0.0f;
      }

    __syncthreads();   // drains prefetch DMA; releases buffer p
    p ^= 1;
  }

  // write chunk composition: layout [c][b][o]
  #pragma unroll
  for (int mt = 0; mt < 4; ++mt)
    #pragma unroll
    for (int reg = 0; reg < 4; ++reg) {
      int s = mt * 4 + reg;
      int b = mt * 16 + quad * 4 + reg;
      size_t idx = ((size_t)c * BB + b) * OO + o;
      chunkA[idx] = SA[s];
      chunkB[idx] = SB[s];
    }
}

// ---------------- kernel 4: fold chunks ----------------
__global__ void combine_k(const float* __restrict__ cA,
                          const float* __restrict__ cB,
                          float* __restrict__ out) {
  int i = blockIdx.x * blockDim.x + threadIdx.x;  // b*OO + o
  float y = 0.0f;
  #pragma unroll 8
  for (int c = 0; c < NCH; c++) {
    float A  = cA[(size_t)c * (BB * OO) + i];
    float Bv = cB[(size_t)c * (BB * OO) + i];
    y = fmaf(A, y, Bv);
  }
  out[i] = y;
}

extern "C" void kernel_launch(void* const* d_in, const int* in_sizes, int n_in,
                              void* d_out, int out_size, void* d_ws, size_t ws_size,
                              hipStream_t stream) {
  (void)in_sizes; (void)n_in; (void)out_size; (void)ws_size;
  const float* x  = (const float*)d_in[0];
  const float* g  = (const float*)d_in[1];
  const float* gb = (const float*)d_in[2];
  const float* h  = (const float*)d_in[3];
  const float* hb = (const float*)d_in[4];
  const float* r  = (const float*)d_in[5];
  const float* rb = (const float*)d_in[6];
  float* out = (float*)d_out;

  char* w = (char*)d_ws;
  unsigned short* xb = (unsigned short*)w;                       // 134217728 B
  unsigned short* Gt = (unsigned short*)(w + 134217728);         // 524288 B
  unsigned short* Ht = (unsigned short*)(w + 134742016);         // 524288 B
  float* chunkA = (float*)(w + 135266304);                       // 8388608 B
  float* chunkB = (float*)(w + 143654912);                       // 8388608 B
  // total: 152043520 B

  static bool attr_set = false;
  if (!attr_set) {
    hipFuncSetAttribute(reinterpret_cast<const void*>(rnn_fused3_k),
                        hipFuncAttributeMaxDynamicSharedMemorySize, 131072);
    attr_set = true;
  }

  const int n4 = (TT * BB * KK) / 4;  // 16777216 float4s
  convert_x_k<<<8192, 256, 0, stream>>>((const float4*)x, (ushort4*)xb, n4);
  prep_weights_k<<<dim3(16, 16, 2), dim3(32, 8), 0, stream>>>(g, h, Gt, Ht);
  rnn_fused3_k<<<NCH * 4, 512, 131072, stream>>>(xb, Gt, Ht, gb, hb, r, rb,
                                                 chunkA, chunkB);
  combine_k<<<(BB * OO) / 256, 256, 0, stream>>>(chunkA, chunkB, out);
}